// Round 1
// 83.513 us; speedup vs baseline: 1.0600x; 1.0600x over previous
//
#include <hip/hip_runtime.h>

// PointWarping2 = flash-attention with head-dim 3:
//   flow2 = softmax(-d2/s^2) @ f1  (no max-tracking; Schraudolph exp2).
// R18: move score GEMM and accumulation GEMM to MFMA (32x32x16 bf16);
// VALU keeps only exp (max + lshl_add) + bf16 truncate-pack (v_perm).
//
// Score MFMA: D[src][q] = sum_k A[src][k]*B[k][q] + 0
//   A (per source, bf16 hi/lo splits, K=16):
//     k0-7  (lanes<32,  srcA): yx_h, yx_l, yx_h, yy_h, yy_l, yy_h, yz_h, yz_l
//     k8-15 (lanes>=32, srcB): yz_h, w_h,  w_l,  1,    1,    1,    0, 0
//       (w = -c1*|y|^2, fp32 then hi/lo bf16)
//   B (per query):
//     k0-7 : Xh, Xh, Xl, Yh, Yh, Yl, Zh, Zh      (Xc = 2*c1*x, hi/lo)
//     k8-15: Zl, 1,  1,  MAGIC(0x4740 exact), qc_h, qc_l, 0, 0
//   => D = MAGIC - c1*d2 exactly as R12's arg.
// PV MFMA: D layout (col=lane&31=q, row=(reg&3)+8*(reg>>2)+4*(lane>>5)=src)
//   means pack(d[2j],d[2j+1]) IS the PV B-operand if values are pre-permuted
//   {0,1,2,3,8,9,10,11 | 4,5,6,7,12,13,14,15} per 16-source group (done in
//   pack kernel -> fpk). acc regs 0-3 on lanes<32 = (nx,ny,nz,den) per query.

#define N1S  8192
#define N2S  8192
#define BATCH 2
#define NS   (BATCH * N1S)       // 16384 sources
#define NQ   (BATCH * N2S)       // 16384 queries
#define GA   (NS + 128)          // guarded stride for srcA/srcB
#define NF   (NS/2 + 64)         // fpk records + guard
#define BLK  512                 // 8 waves; each wave: 1024 sources = 32 tiles
#define LOG2E 1.4426950408889634f
#define MAGIC 49152.0f           // 1.5*2^15
#define CLAMPS (MAGIC - 120.0f)
#define KBITS 1064990910         // (127<<23) - 362306: rel err +-3.04%
#define ONEB 0x3F80u             // bf16(1.0)
#define MAGB 0x4740u             // bf16(49152.0), exact

typedef __attribute__((ext_vector_type(8)))  short bf16x8;
typedef __attribute__((ext_vector_type(16))) float f32x16;

__device__ __forceinline__ float read_scale(const void* p) {
    // resol_factor: 1-elem array; Python int -> int32, float -> fp32.
    int iv = *(const int*)p;
    if (iv > -(1 << 23) && iv < (1 << 23)) return (float)iv;
    return *(const float*)p;
}

__device__ __forceinline__ unsigned bf16_rne(float v) {   // round-nearest-even
    unsigned u = __builtin_bit_cast(unsigned, v);
    return (u + 0x7FFFu + ((u >> 16) & 1u)) >> 16;
}

__device__ __forceinline__ float bfh2f(unsigned b16) {    // bf16 bits -> fp32
    return __builtin_bit_cast(float, b16 << 16);
}

// pack top-16 (truncated bf16) of two u32 weight words: {hi16(uo), hi16(ue)}
__device__ __forceinline__ unsigned pkhi(unsigned uo, unsigned ue) {
    return __builtin_amdgcn_perm(uo, ue, 0x07060302u);
}

// ---- k1: build srcA/srcB (score A-operand) and fpk (PV A-operand) ----
__global__ __launch_bounds__(256) void pw2_pack(
    const float* __restrict__ xyz1, const float* __restrict__ flow1,
    const void* __restrict__ resol, uint4* __restrict__ srcA,
    uint4* __restrict__ srcB, uint4* __restrict__ fpk)
{
    const int i = blockIdx.x * 256 + threadIdx.x;
    const float scale = read_scale(resol);
    const float c1 = LOG2E / (scale * scale);

    if (i < NS) {
        const int b = i >> 13, m = i & (N1S - 1);
        const float* x1b = xyz1  + b * 3 * N1S;
        const float* f1b = flow1 + b * 3 * N1S;
        float fx = f1b[0*N1S+m], fy = f1b[1*N1S+m], fz = f1b[2*N1S+m];
        float yx = x1b[0*N1S+m]+fx, yy = x1b[1*N1S+m]+fy, yz = x1b[2*N1S+m]+fz;
        float wq = -c1 * (yx*yx + yy*yy + yz*yz);   // fp32-exact, then split
        unsigned xh = bf16_rne(yx), yh = bf16_rne(yy), zh = bf16_rne(yz);
        unsigned xl = bf16_rne(yx - bfh2f(xh));
        unsigned yl = bf16_rne(yy - bfh2f(yh));
        unsigned zl = bf16_rne(yz - bfh2f(zh));
        unsigned wh = bf16_rne(wq);
        unsigned wl = bf16_rne(wq - bfh2f(wh));
        uint4 A;                                   // k0-7, low-half-first
        A.x = xh | (xl << 16);
        A.y = xh | (yh << 16);
        A.z = yl | (yh << 16);
        A.w = zh | (zl << 16);
        srcA[i] = A;
        uint4 Bv;                                  // k8-15
        Bv.x = zh | (wh << 16);
        Bv.y = wl | (ONEB << 16);
        Bv.z = ONEB | (ONEB << 16);
        Bv.w = 0u;
        srcB[i] = Bv;
    }

    if (i < NS / 2) {
        // fpk record i: group g of 16 sources, half h, component c.
        // k-order permutation per group: h=0 -> {0,1,2,3,8,9,10,11},
        //                                h=1 -> {4,5,6,7,12,13,14,15}.
        const int g = i >> 3, h = (i >> 2) & 1, c = i & 3;
        const int b = g >> 9, m0 = (g & 511) * 16;
        const float* f1c = flow1 + b * 3 * N1S + (c < 3 ? c : 0) * N1S;
        const int base = h * 4;
        unsigned e[8];
#pragma unroll
        for (int j = 0; j < 8; ++j) {
            int s = m0 + base + (j & 3) + (j >> 2) * 8;
            e[j] = (c == 3) ? ONEB : bf16_rne(f1c[s]);
        }
        uint4 F;
        F.x = e[0] | (e[1] << 16);
        F.y = e[2] | (e[3] << 16);
        F.z = e[4] | (e[5] << 16);
        F.w = e[6] | (e[7] << 16);
        fpk[i] = F;
    }
}

// ---- k2: MFMA main kernel ----
__global__ __launch_bounds__(BLK, 2) void pw2_main(
    const uint4* __restrict__ srcA, const uint4* __restrict__ srcB,
    const uint4* __restrict__ fpk, const float* __restrict__ xyz2,
    const void* __restrict__ resol, float* __restrict__ out)
{
    __shared__ float4 red[8][32];     // [wave][query] partial (nx,ny,nz,den)

    const int t  = threadIdx.x;
    const int w  = t >> 6, l = t & 63, lq = l & 31, hi = l >> 5;
    const int qblk  = blockIdx.x * 32;
    const int b     = qblk >> 13;
    const int nbase = qblk & (N2S - 1);

    const float scale = read_scale(resol);
    const float c1 = LOG2E / (scale * scale), twoC = 2.0f * c1;
    const float* x2b = xyz2 + b * 3 * N2S;

    // ---- per-lane query constants -> score B fragment (col = lq) ----
    const int n = nbase + lq;
    const float qx = x2b[0*N2S+n], qy = x2b[1*N2S+n], qz = x2b[2*N2S+n];
    const float Xc = twoC*qx, Yc = twoC*qy, Zc = twoC*qz;
    unsigned Xh = bf16_rne(Xc), Yh = bf16_rne(Yc), Zh = bf16_rne(Zc);
    unsigned Xl = bf16_rne(Xc - bfh2f(Xh));
    unsigned Yl = bf16_rne(Yc - bfh2f(Yh));
    unsigned Zl = bf16_rne(Zc - bfh2f(Zh));
    const float qc = -c1 * (qx*qx + qy*qy + qz*qz);
    unsigned Qh = bf16_rne(qc);
    unsigned Ql = bf16_rne(qc - bfh2f(Qh));
    uint4 bw;
    bw.x = hi ? (Zl | (ONEB << 16)) : (Xh | (Xh << 16));
    bw.y = hi ? (ONEB | (MAGB << 16)) : (Xl | (Yh << 16));
    bw.z = hi ? (Qh | (Ql << 16)) : (Yh | (Yl << 16));
    bw.w = hi ? 0u : (Zh | (Zh << 16));
    const bf16x8 Bf = __builtin_bit_cast(bf16x8, bw);

    f32x16 acc, zc;
#pragma unroll
    for (int k = 0; k < 16; ++k) { acc[k] = 0.f; zc[k] = 0.f; }

    // ---- source loop: 32 tiles x 32 sources, depth-1 guarded prefetch ----
    const uint4* ap = hi ? srcB : srcA;
    int ia = b * N1S + w * 1024 + lq;
    int ir = ((b * N1S + w * 1024) >> 4) * 8 + hi * 4 + (l & 3);

    uint4 sA = ap[ia];
    uint4 f0 = fpk[ir];
    uint4 f1 = fpk[ir + 8];

#pragma unroll 2
    for (int tt = 0; tt < 32; ++tt) {
        const uint4 sA_n = ap[ia + 32];        // guard arrays: always legal
        const uint4 f0_n = fpk[ir + 16];
        const uint4 f1_n = fpk[ir + 24];

        f32x16 d = __builtin_amdgcn_mfma_f32_32x32x16_bf16(
            __builtin_bit_cast(bf16x8, sA), Bf, zc, 0, 0, 0);

        unsigned u[16];
#pragma unroll
        for (int k = 0; k < 16; ++k) {
            float s = fmaxf(d[k], CLAMPS);
            u[k] = (unsigned)((__builtin_bit_cast(int, s) << 15) + KBITS);
        }
        uint4 p0, p1;
        p0.x = pkhi(u[1],  u[0]);  p0.y = pkhi(u[3],  u[2]);
        p0.z = pkhi(u[5],  u[4]);  p0.w = pkhi(u[7],  u[6]);
        p1.x = pkhi(u[9],  u[8]);  p1.y = pkhi(u[11], u[10]);
        p1.z = pkhi(u[13], u[12]); p1.w = pkhi(u[15], u[14]);

        acc = __builtin_amdgcn_mfma_f32_32x32x16_bf16(
            __builtin_bit_cast(bf16x8, f0), __builtin_bit_cast(bf16x8, p0),
            acc, 0, 0, 0);
        acc = __builtin_amdgcn_mfma_f32_32x32x16_bf16(
            __builtin_bit_cast(bf16x8, f1), __builtin_bit_cast(bf16x8, p1),
            acc, 0, 0, 0);

        sA = sA_n; f0 = f0_n; f1 = f1_n;
        ia += 32; ir += 16;
    }

    // ---- cross-wave reduce + normalize + write ----
    if (hi == 0) red[w][lq] = make_float4(acc[0], acc[1], acc[2], acc[3]);
    __syncthreads();
    if (t < 32) {
        float nx = 0.f, ny = 0.f, nz = 0.f, dn = 0.f;
#pragma unroll
        for (int ww = 0; ww < 8; ++ww) {
            float4 r = red[ww][t];
            nx += r.x; ny += r.y; nz += r.z; dn += r.w;
        }
        const float inv = 1.0f / dn;
        const int nq = nbase + t;
        out[b*3*N2S + 0*N2S + nq] = x2b[0*N2S+nq] - nx * inv;
        out[b*3*N2S + 1*N2S + nq] = x2b[1*N2S+nq] - ny * inv;
        out[b*3*N2S + 2*N2S + nq] = x2b[2*N2S+nq] - nz * inv;
    }
}

extern "C" void kernel_launch(void* const* d_in, const int* in_sizes, int n_in,
                              void* d_out, int out_size, void* d_ws, size_t ws_size,
                              hipStream_t stream) {
    const float* xyz1  = (const float*)d_in[0];
    const float* xyz2  = (const float*)d_in[1];
    const float* flow1 = (const float*)d_in[2];
    const void*  resol = d_in[3];
    float* out = (float*)d_out;

    uint4* srcA = (uint4*)d_ws;        // GA records
    uint4* srcB = srcA + GA;           // GA records
    uint4* fpk  = srcB + GA;           // NF records; total ~660 KB

    pw2_pack<<<NS / 256, 256, 0, stream>>>(xyz1, flow1, resol, srcA, srcB, fpk);
    pw2_main<<<NQ / 32, BLK, 0, stream>>>(srcA, srcB, fpk, xyz2, resol, out);
}

// Round 2
// 82.242 us; speedup vs baseline: 1.0764x; 1.0155x over previous
//
#include <hip/hip_runtime.h>

// PointWarping2 = flash-attention with head-dim 3:
//   flow2 = softmax(-d2/s^2) @ f1  (no max-tracking; Schraudolph exp2).
// R19: software-pipeline the score MFMA one tile ahead so the exp/pack
// VALU phase of tile t hides the score-MFMA latency of tile t+1, and
// interleave the two exp half-packs with the two PV MFMA issues.
// (R18 measured 83.5us total; serial score->exp->PV chain left ~10us of
// dependency stall in pw2_main. PV acc-chain is HW-pipelined; score isn't.)
//
// Score MFMA: D[src][q] = sum_k A[src][k]*B[k][q] + 0
//   A (per source, bf16 hi/lo splits, K=16):
//     k0-7  (lanes<32,  srcA): yx_h, yx_l, yx_h, yy_h, yy_l, yy_h, yz_h, yz_l
//     k8-15 (lanes>=32, srcB): yz_h, w_h,  w_l,  1,    1,    1,    0, 0
//       (w = -c1*|y|^2, fp32 then hi/lo bf16)
//   B (per query):
//     k0-7 : Xh, Xh, Xl, Yh, Yh, Yl, Zh, Zh      (Xc = 2*c1*x, hi/lo)
//     k8-15: Zl, 1,  1,  MAGIC(0x4740 exact), qc_h, qc_l, 0, 0
//   => D = MAGIC - c1*d2 exactly as R12's arg.
// PV MFMA: D layout (col=lane&31=q, row=(reg&3)+8*(reg>>2)+4*(lane>>5)=src)
//   means pack(d[2j],d[2j+1]) IS the PV B-operand if values are pre-permuted
//   {0,1,2,3,8,9,10,11 | 4,5,6,7,12,13,14,15} per 16-source group (done in
//   pack kernel -> fpk). acc regs 0-3 on lanes<32 = (nx,ny,nz,den) per query.

#define N1S  8192
#define N2S  8192
#define BATCH 2
#define NS   (BATCH * N1S)       // 16384 sources
#define NQ   (BATCH * N2S)       // 16384 queries
#define GA   (NS + 128)          // guarded stride for srcA/srcB
#define NF   (NS/2 + 64)         // fpk records + guard
#define BLK  512                 // 8 waves; each wave: 1024 sources = 32 tiles
#define LOG2E 1.4426950408889634f
#define MAGIC 49152.0f           // 1.5*2^15
#define CLAMPS (MAGIC - 120.0f)
#define KBITS 1064990910         // (127<<23) - 362306: rel err +-3.04%
#define ONEB 0x3F80u             // bf16(1.0)
#define MAGB 0x4740u             // bf16(49152.0), exact

typedef __attribute__((ext_vector_type(8)))  short bf16x8;
typedef __attribute__((ext_vector_type(16))) float f32x16;

__device__ __forceinline__ float read_scale(const void* p) {
    // resol_factor: 1-elem array; Python int -> int32, float -> fp32.
    int iv = *(const int*)p;
    if (iv > -(1 << 23) && iv < (1 << 23)) return (float)iv;
    return *(const float*)p;
}

__device__ __forceinline__ unsigned bf16_rne(float v) {   // round-nearest-even
    unsigned u = __builtin_bit_cast(unsigned, v);
    return (u + 0x7FFFu + ((u >> 16) & 1u)) >> 16;
}

__device__ __forceinline__ float bfh2f(unsigned b16) {    // bf16 bits -> fp32
    return __builtin_bit_cast(float, b16 << 16);
}

// pack top-16 (truncated bf16) of two u32 weight words: {hi16(uo), hi16(ue)}
__device__ __forceinline__ unsigned pkhi(unsigned uo, unsigned ue) {
    return __builtin_amdgcn_perm(uo, ue, 0x07060302u);
}

// ---- k1: build srcA/srcB (score A-operand) and fpk (PV A-operand) ----
__global__ __launch_bounds__(256) void pw2_pack(
    const float* __restrict__ xyz1, const float* __restrict__ flow1,
    const void* __restrict__ resol, uint4* __restrict__ srcA,
    uint4* __restrict__ srcB, uint4* __restrict__ fpk)
{
    const int i = blockIdx.x * 256 + threadIdx.x;
    const float scale = read_scale(resol);
    const float c1 = LOG2E / (scale * scale);

    if (i < NS) {
        const int b = i >> 13, m = i & (N1S - 1);
        const float* x1b = xyz1  + b * 3 * N1S;
        const float* f1b = flow1 + b * 3 * N1S;
        float fx = f1b[0*N1S+m], fy = f1b[1*N1S+m], fz = f1b[2*N1S+m];
        float yx = x1b[0*N1S+m]+fx, yy = x1b[1*N1S+m]+fy, yz = x1b[2*N1S+m]+fz;
        float wq = -c1 * (yx*yx + yy*yy + yz*yz);   // fp32-exact, then split
        unsigned xh = bf16_rne(yx), yh = bf16_rne(yy), zh = bf16_rne(yz);
        unsigned xl = bf16_rne(yx - bfh2f(xh));
        unsigned yl = bf16_rne(yy - bfh2f(yh));
        unsigned zl = bf16_rne(yz - bfh2f(zh));
        unsigned wh = bf16_rne(wq);
        unsigned wl = bf16_rne(wq - bfh2f(wh));
        uint4 A;                                   // k0-7, low-half-first
        A.x = xh | (xl << 16);
        A.y = xh | (yh << 16);
        A.z = yl | (yh << 16);
        A.w = zh | (zl << 16);
        srcA[i] = A;
        uint4 Bv;                                  // k8-15
        Bv.x = zh | (wh << 16);
        Bv.y = wl | (ONEB << 16);
        Bv.z = ONEB | (ONEB << 16);
        Bv.w = 0u;
        srcB[i] = Bv;
    }

    if (i < NS / 2) {
        // fpk record i: group g of 16 sources, half h, component c.
        // k-order permutation per group: h=0 -> {0,1,2,3,8,9,10,11},
        //                                h=1 -> {4,5,6,7,12,13,14,15}.
        const int g = i >> 3, h = (i >> 2) & 1, c = i & 3;
        const int b = g >> 9, m0 = (g & 511) * 16;
        const float* f1c = flow1 + b * 3 * N1S + (c < 3 ? c : 0) * N1S;
        const int base = h * 4;
        unsigned e[8];
#pragma unroll
        for (int j = 0; j < 8; ++j) {
            int s = m0 + base + (j & 3) + (j >> 2) * 8;
            e[j] = (c == 3) ? ONEB : bf16_rne(f1c[s]);
        }
        uint4 F;
        F.x = e[0] | (e[1] << 16);
        F.y = e[2] | (e[3] << 16);
        F.z = e[4] | (e[5] << 16);
        F.w = e[6] | (e[7] << 16);
        fpk[i] = F;
    }
}

// ---- k2: MFMA main kernel ----
__global__ __launch_bounds__(BLK, 2) void pw2_main(
    const uint4* __restrict__ srcA, const uint4* __restrict__ srcB,
    const uint4* __restrict__ fpk, const float* __restrict__ xyz2,
    const void* __restrict__ resol, float* __restrict__ out)
{
    __shared__ float4 red[8][32];     // [wave][query] partial (nx,ny,nz,den)

    const int t  = threadIdx.x;
    const int w  = t >> 6, l = t & 63, lq = l & 31, hi = l >> 5;
    const int qblk  = blockIdx.x * 32;
    const int b     = qblk >> 13;
    const int nbase = qblk & (N2S - 1);

    const float scale = read_scale(resol);
    const float c1 = LOG2E / (scale * scale), twoC = 2.0f * c1;
    const float* x2b = xyz2 + b * 3 * N2S;

    // ---- per-lane query constants -> score B fragment (col = lq) ----
    const int n = nbase + lq;
    const float qx = x2b[0*N2S+n], qy = x2b[1*N2S+n], qz = x2b[2*N2S+n];
    const float Xc = twoC*qx, Yc = twoC*qy, Zc = twoC*qz;
    unsigned Xh = bf16_rne(Xc), Yh = bf16_rne(Yc), Zh = bf16_rne(Zc);
    unsigned Xl = bf16_rne(Xc - bfh2f(Xh));
    unsigned Yl = bf16_rne(Yc - bfh2f(Yh));
    unsigned Zl = bf16_rne(Zc - bfh2f(Zh));
    const float qc = -c1 * (qx*qx + qy*qy + qz*qz);
    unsigned Qh = bf16_rne(qc);
    unsigned Ql = bf16_rne(qc - bfh2f(Qh));
    uint4 bw;
    bw.x = hi ? (Zl | (ONEB << 16)) : (Xh | (Xh << 16));
    bw.y = hi ? (ONEB | (MAGB << 16)) : (Xl | (Yh << 16));
    bw.z = hi ? (Qh | (Ql << 16)) : (Yh | (Yl << 16));
    bw.w = hi ? 0u : (Zh | (Zh << 16));
    const bf16x8 Bf = __builtin_bit_cast(bf16x8, bw);

    f32x16 acc, zc;
#pragma unroll
    for (int k = 0; k < 16; ++k) { acc[k] = 0.f; zc[k] = 0.f; }

    // ---- source loop: 32 tiles x 32 sources, score pipelined 1 ahead ----
    const uint4* ap = hi ? srcB : srcA;
    int ia = b * N1S + w * 1024 + lq;
    int ir = ((b * N1S + w * 1024) >> 4) * 8 + hi * 4 + (l & 3);

    uint4 sA  = ap[ia];            // tile 0 score operand
    uint4 f0  = fpk[ir];           // tile 0 PV operands
    uint4 f1  = fpk[ir + 8];
    uint4 sA1 = ap[ia + 32];       // tile 1 score operand

    // d = scores of tile 0 (computed ahead of the loop body that uses it)
    f32x16 d = __builtin_amdgcn_mfma_f32_32x32x16_bf16(
        __builtin_bit_cast(bf16x8, sA), Bf, zc, 0, 0, 0);

#pragma unroll 2
    for (int tt = 0; tt < 32; ++tt) {
        // prefetch: tile tt+2 score operand, tile tt+1 PV operands
        const uint4 sA2  = ap[ia + 64];        // guard arrays: always legal
        const uint4 f0_n = fpk[ir + 16];
        const uint4 f1_n = fpk[ir + 24];

        // issue NEXT tile's score MFMA before consuming this tile's d:
        // its ~34cy latency hides under the exp/pack VALU phase below.
        // (tt==31: operands are guard garbage; d_next is never consumed.)
        const f32x16 d_next = __builtin_amdgcn_mfma_f32_32x32x16_bf16(
            __builtin_bit_cast(bf16x8, sA1), Bf, zc, 0, 0, 0);

        // exp/pack first half -> PV0, second half -> PV1 (interleaved to
        // shrink transient u[] pressure and overlap VALU with MFMA issue)
        unsigned u0, u1, u2, u3, u4, u5, u6, u7;
        uint4 p;
        {
            float s0 = fmaxf(d[0], CLAMPS), s1 = fmaxf(d[1], CLAMPS);
            float s2 = fmaxf(d[2], CLAMPS), s3 = fmaxf(d[3], CLAMPS);
            float s4 = fmaxf(d[4], CLAMPS), s5 = fmaxf(d[5], CLAMPS);
            float s6 = fmaxf(d[6], CLAMPS), s7 = fmaxf(d[7], CLAMPS);
            u0 = (unsigned)((__builtin_bit_cast(int, s0) << 15) + KBITS);
            u1 = (unsigned)((__builtin_bit_cast(int, s1) << 15) + KBITS);
            u2 = (unsigned)((__builtin_bit_cast(int, s2) << 15) + KBITS);
            u3 = (unsigned)((__builtin_bit_cast(int, s3) << 15) + KBITS);
            u4 = (unsigned)((__builtin_bit_cast(int, s4) << 15) + KBITS);
            u5 = (unsigned)((__builtin_bit_cast(int, s5) << 15) + KBITS);
            u6 = (unsigned)((__builtin_bit_cast(int, s6) << 15) + KBITS);
            u7 = (unsigned)((__builtin_bit_cast(int, s7) << 15) + KBITS);
            p.x = pkhi(u1, u0); p.y = pkhi(u3, u2);
            p.z = pkhi(u5, u4); p.w = pkhi(u7, u6);
        }
        acc = __builtin_amdgcn_mfma_f32_32x32x16_bf16(
            __builtin_bit_cast(bf16x8, f0), __builtin_bit_cast(bf16x8, p),
            acc, 0, 0, 0);
        {
            float s0 = fmaxf(d[8],  CLAMPS), s1 = fmaxf(d[9],  CLAMPS);
            float s2 = fmaxf(d[10], CLAMPS), s3 = fmaxf(d[11], CLAMPS);
            float s4 = fmaxf(d[12], CLAMPS), s5 = fmaxf(d[13], CLAMPS);
            float s6 = fmaxf(d[14], CLAMPS), s7 = fmaxf(d[15], CLAMPS);
            u0 = (unsigned)((__builtin_bit_cast(int, s0) << 15) + KBITS);
            u1 = (unsigned)((__builtin_bit_cast(int, s1) << 15) + KBITS);
            u2 = (unsigned)((__builtin_bit_cast(int, s2) << 15) + KBITS);
            u3 = (unsigned)((__builtin_bit_cast(int, s3) << 15) + KBITS);
            u4 = (unsigned)((__builtin_bit_cast(int, s4) << 15) + KBITS);
            u5 = (unsigned)((__builtin_bit_cast(int, s5) << 15) + KBITS);
            u6 = (unsigned)((__builtin_bit_cast(int, s6) << 15) + KBITS);
            u7 = (unsigned)((__builtin_bit_cast(int, s7) << 15) + KBITS);
            p.x = pkhi(u1, u0); p.y = pkhi(u3, u2);
            p.z = pkhi(u5, u4); p.w = pkhi(u7, u6);
        }
        acc = __builtin_amdgcn_mfma_f32_32x32x16_bf16(
            __builtin_bit_cast(bf16x8, f1), __builtin_bit_cast(bf16x8, p),
            acc, 0, 0, 0);

        // rotate pipeline registers
        d = d_next; sA1 = sA2; f0 = f0_n; f1 = f1_n;
        ia += 32; ir += 16;
    }

    // ---- cross-wave reduce + normalize + write ----
    if (hi == 0) red[w][lq] = make_float4(acc[0], acc[1], acc[2], acc[3]);
    __syncthreads();
    if (t < 32) {
        float nx = 0.f, ny = 0.f, nz = 0.f, dn = 0.f;
#pragma unroll
        for (int ww = 0; ww < 8; ++ww) {
            float4 r = red[ww][t];
            nx += r.x; ny += r.y; nz += r.z; dn += r.w;
        }
        const float inv = 1.0f / dn;
        const int nq = nbase + t;
        out[b*3*N2S + 0*N2S + nq] = x2b[0*N2S+nq] - nx * inv;
        out[b*3*N2S + 1*N2S + nq] = x2b[1*N2S+nq] - ny * inv;
        out[b*3*N2S + 2*N2S + nq] = x2b[2*N2S+nq] - nz * inv;
    }
}

extern "C" void kernel_launch(void* const* d_in, const int* in_sizes, int n_in,
                              void* d_out, int out_size, void* d_ws, size_t ws_size,
                              hipStream_t stream) {
    const float* xyz1  = (const float*)d_in[0];
    const float* xyz2  = (const float*)d_in[1];
    const float* flow1 = (const float*)d_in[2];
    const void*  resol = d_in[3];
    float* out = (float*)d_out;

    uint4* srcA = (uint4*)d_ws;        // GA records
    uint4* srcB = srcA + GA;           // GA records
    uint4* fpk  = srcB + GA;           // NF records; total ~660 KB

    pw2_pack<<<NS / 256, 256, 0, stream>>>(xyz1, flow1, resol, srcA, srcB, fpk);
    pw2_main<<<NQ / 32, BLK, 0, stream>>>(srcA, srcB, fpk, xyz2, resol, out);
}